// Round 3
// baseline (409.966 us; speedup 1.0000x reference)
//
#include <hip/hip_runtime.h>
#include <hip/hip_bf16.h>

#define B_ 32
#define C_ 512
#define Q_ 128
#define D_ 768
constexpr float NEGV = -1e30f;

// ---------------- K1: cdot[b,c] = cont . w1 ; qdot[b,q] = ques . w2 (wave per row)
__global__ void k_dots(const float* __restrict__ cont, const float* __restrict__ ques,
                       const float* __restrict__ SW, float* __restrict__ cdot,
                       float* __restrict__ qdot) {
    int w = threadIdx.x >> 6;
    int lane = threadIdx.x & 63;
    int r = blockIdx.x * 4 + w;
    const float* row;
    const float* wv;
    if (r < B_ * C_) { row = cont + (size_t)r * D_; wv = SW; }
    else             { row = ques + (size_t)(r - B_ * C_) * D_; wv = SW + D_; }
    float s = 0.f;
#pragma unroll
    for (int i = 0; i < D_ / 64; ++i) {
        int d = lane + i * 64;
        s += row[d] * wv[d];
    }
#pragma unroll
    for (int off = 32; off; off >>= 1) s += __shfl_xor(s, off, 64);
    if (lane == 0) {
        if (r < B_ * C_) cdot[r] = s;
        else qdot[r - B_ * C_] = s;
    }
}

// ---------------- K2: S[b,c,q] = sum_d cont*w3*ques + cdot + qdot  (64x64 tile, 4x4/thread)
__global__ void k_sim(const float* __restrict__ cont, const float* __restrict__ ques,
                      const float* __restrict__ SW, const float* __restrict__ cdot,
                      const float* __restrict__ qdot, float* __restrict__ S) {
    const int b = blockIdx.z, c0 = blockIdx.x * 64, q0 = blockIdx.y * 64;
    __shared__ __align__(16) float As[16][68];
    __shared__ __align__(16) float Bs[16][68];
    const int tid = threadIdx.x;
    const int tx = tid & 15, ty = tid >> 4;
    const int lr = tid >> 2;           // tile row (c or q), 0..63
    const int lk = (tid & 3) * 4;      // k base within 16
    const float* w3 = SW + 2 * D_;
    float acc[4][4] = {};
    const float* Abase = cont + ((size_t)(b * C_ + c0 + lr)) * D_ + lk;
    const float* Bbase = ques + ((size_t)(b * Q_ + q0 + lr)) * D_ + lk;
    for (int k0 = 0; k0 < D_; k0 += 16) {
        float4 av = *(const float4*)(Abase + k0);
        float4 bv = *(const float4*)(Bbase + k0);
        As[lk + 0][lr] = av.x * w3[k0 + lk + 0];
        As[lk + 1][lr] = av.y * w3[k0 + lk + 1];
        As[lk + 2][lr] = av.z * w3[k0 + lk + 2];
        As[lk + 3][lr] = av.w * w3[k0 + lk + 3];
        Bs[lk + 0][lr] = bv.x;
        Bs[lk + 1][lr] = bv.y;
        Bs[lk + 2][lr] = bv.z;
        Bs[lk + 3][lr] = bv.w;
        __syncthreads();
#pragma unroll
        for (int k = 0; k < 16; ++k) {
            float4 a4 = *(const float4*)&As[k][ty * 4];
            float4 b4 = *(const float4*)&Bs[k][tx * 4];
            float a[4] = {a4.x, a4.y, a4.z, a4.w};
            float bb[4] = {b4.x, b4.y, b4.z, b4.w};
#pragma unroll
            for (int i = 0; i < 4; ++i)
#pragma unroll
                for (int j = 0; j < 4; ++j) acc[i][j] += a[i] * bb[j];
        }
        __syncthreads();
    }
#pragma unroll
    for (int i = 0; i < 4; ++i) {
        int c = c0 + ty * 4 + i;
        float cd = cdot[b * C_ + c];
        int q = q0 + tx * 4;
        float4 o;
        o.x = acc[i][0] + cd + qdot[b * Q_ + q + 0];
        o.y = acc[i][1] + cd + qdot[b * Q_ + q + 1];
        o.z = acc[i][2] + cd + qdot[b * Q_ + q + 2];
        o.w = acc[i][3] + cd + qdot[b * Q_ + q + 3];
        *(float4*)(S + ((size_t)(b * C_ + c)) * Q_ + q) = o;
    }
}

// ---------------- K3: per (b,q): m = max_c S, invL = 1/sum_c exp(S-m)
__global__ void k_colstats(const float* __restrict__ S, float* __restrict__ colM,
                           float* __restrict__ colInvL) {
    int b = blockIdx.x;
    int q = threadIdx.x & 127;
    int chunk = threadIdx.x >> 7;   // 0..3, 128 c each
    float m = -INFINITY, l = 0.f;
    const float* Sp = S + ((size_t)(b * C_ + chunk * 128)) * Q_ + q;
    for (int c = 0; c < 128; ++c) {
        float v = Sp[(size_t)c * Q_];
        if (v > m) { l = l * __expf(m - v) + 1.f; m = v; }
        else l += __expf(v - m);
    }
    __shared__ float sm[4][128], sl[4][128];
    sm[chunk][q] = m; sl[chunk][q] = l;
    __syncthreads();
    if (chunk == 0) {
        float M = sm[0][q], L = sl[0][q];
#pragma unroll
        for (int i = 1; i < 4; ++i) {
            float mi = sm[i][q], li = sl[i][q];
            if (mi > M) { L = L * __expf(M - mi) + li; M = mi; }
            else L += li * __expf(mi - M);
        }
        colM[b * Q_ + q] = M;
        colInvL[b * Q_ + q] = 1.f / L;
    }
}

// ---------------- K4a: Smax[b,c] = max_q S  (wave per row)
__global__ void k_rowmax(const float* __restrict__ S, float* __restrict__ Smax) {
    int w = threadIdx.x >> 6, lane = threadIdx.x & 63;
    int r = blockIdx.x * 4 + w;   // 0..B*C-1
    const float* Sp = S + (size_t)r * Q_;
    float m = fmaxf(Sp[lane], Sp[lane + 64]);
#pragma unroll
    for (int off = 32; off; off >>= 1) m = fmaxf(m, __shfl_xor(m, off, 64));
    if (lane == 0) Smax[r] = m;
}

// ---------------- K4b: c_dash[b,d] = sum_c softmax_c(Smax + cmask)*cont
__global__ void k_cdash(const float* __restrict__ cont, const int* __restrict__ cmask,
                        const float* __restrict__ Smax, float* __restrict__ cdash) {
    int b = blockIdx.x, dchunk = blockIdx.y;
    __shared__ float dist[C_];
    __shared__ float red[256];
    int tid = threadIdx.x;
    float v0 = Smax[b * C_ + tid]       + (cmask[b * C_ + tid]       ? 0.f : NEGV);
    float v1 = Smax[b * C_ + tid + 256] + (cmask[b * C_ + tid + 256] ? 0.f : NEGV);
    float m = fmaxf(v0, v1);
    red[tid] = m; __syncthreads();
    for (int s = 128; s; s >>= 1) { if (tid < s) red[tid] = fmaxf(red[tid], red[tid + s]); __syncthreads(); }
    m = red[0]; __syncthreads();
    float e0 = __expf(v0 - m), e1 = __expf(v1 - m);
    red[tid] = e0 + e1; __syncthreads();
    for (int s = 128; s; s >>= 1) { if (tid < s) red[tid] += red[tid + s]; __syncthreads(); }
    float inv = 1.f / red[0];
    dist[tid] = e0 * inv; dist[tid + 256] = e1 * inv;
    __syncthreads();
    int d = dchunk * 256 + tid;
    float acc = 0.f;
    const float* cp = cont + ((size_t)(b * C_)) * D_ + d;
    for (int c = 0; c < C_; ++c) acc += dist[c] * cp[(size_t)c * D_];
    cdash[b * D_ + d] = acc;
}

// ---------------- K5: c2q = dist @ ques; write all 4 output sections
__global__ void k_final(const float* __restrict__ cont, const float* __restrict__ ques,
                        const int* __restrict__ qmask, const float* __restrict__ S,
                        const float* __restrict__ colM, const float* __restrict__ colInvL,
                        const float* __restrict__ cdash, float* __restrict__ out) {
    const int b = blockIdx.z, c0 = blockIdx.x * 64, d0 = blockIdx.y * 64;
    __shared__ __align__(16) float As[16][68];   // dist[kq][c]
    __shared__ __align__(16) float Bs[16][68];   // ques[kq][d]
    const int tid = threadIdx.x;
    const int tx = tid & 15, ty = tid >> 4;
    const int lr = tid >> 2, lk = (tid & 3) * 4;   // A loads: c=lr, q=k0+lk+j
    const int br = tid >> 4, bc = (tid & 15) * 4;  // B loads: k=br, d=bc
    float acc[4][4] = {};
    for (int k0 = 0; k0 < Q_; k0 += 16) {
        float4 sv = *(const float4*)(S + ((size_t)(b * C_ + c0 + lr)) * Q_ + k0 + lk);
        float a[4] = {sv.x, sv.y, sv.z, sv.w};
#pragma unroll
        for (int j = 0; j < 4; ++j) {
            int q = k0 + lk + j;
            float dist;
            if (qmask[b * Q_ + q]) dist = __expf(a[j] - colM[b * Q_ + q]) * colInvL[b * Q_ + q];
            else dist = 1.f / C_;
            As[lk + j][lr] = dist;
        }
        float4 bv = *(const float4*)(ques + ((size_t)(b * Q_ + k0 + br)) * D_ + d0 + bc);
        Bs[br][bc + 0] = bv.x; Bs[br][bc + 1] = bv.y;
        Bs[br][bc + 2] = bv.z; Bs[br][bc + 3] = bv.w;
        __syncthreads();
#pragma unroll
        for (int k = 0; k < 16; ++k) {
            float4 a4 = *(const float4*)&As[k][ty * 4];
            float4 b4 = *(const float4*)&Bs[k][tx * 4];
            float aa[4] = {a4.x, a4.y, a4.z, a4.w};
            float bb[4] = {b4.x, b4.y, b4.z, b4.w};
#pragma unroll
            for (int i = 0; i < 4; ++i)
#pragma unroll
                for (int j = 0; j < 4; ++j) acc[i][j] += aa[i] * bb[j];
        }
        __syncthreads();
    }
    int d = d0 + tx * 4;
    float4 dv = *(const float4*)(cdash + b * D_ + d);
#pragma unroll
    for (int i = 0; i < 4; ++i) {
        int c = c0 + ty * 4 + i;
        size_t obase = ((size_t)(b * C_ + c)) * (size_t)(4 * D_);
        float4 cv = *(const float4*)(cont + ((size_t)(b * C_ + c)) * D_ + d);
        float4 a = {acc[i][0], acc[i][1], acc[i][2], acc[i][3]};
        float4 t = {cv.x * a.x, cv.y * a.y, cv.z * a.z, cv.w * a.w};
        float4 u = {cv.x * dv.x, cv.y * dv.y, cv.z * dv.z, cv.w * dv.w};
        *(float4*)(out + obase + d) = cv;
        *(float4*)(out + obase + D_ + d) = a;
        *(float4*)(out + obase + 2 * D_ + d) = t;
        *(float4*)(out + obase + 3 * D_ + d) = u;
    }
}

extern "C" void kernel_launch(void* const* d_in, const int* in_sizes, int n_in,
                              void* d_out, int out_size, void* d_ws, size_t ws_size,
                              hipStream_t stream) {
    const float* cont  = (const float*)d_in[0];
    const int*   cmask = (const int*)d_in[1];
    const float* ques  = (const float*)d_in[2];
    const int*   qmask = (const int*)d_in[3];
    const float* SW    = (const float*)d_in[4];
    float* out = (float*)d_out;

    float* ws      = (float*)d_ws;
    float* S       = ws;                               // B*C*Q = 2,097,152
    float* Smax    = S + (size_t)B_ * C_ * Q_;         // B*C   = 16,384
    float* colM    = Smax + B_ * C_;                   // B*Q   = 4,096
    float* colInvL = colM + B_ * Q_;                   // B*Q   = 4,096
    float* cdot    = colInvL + B_ * Q_;                // B*C   = 16,384
    float* qdot    = cdot + B_ * C_;                   // B*Q   = 4,096
    float* cdash   = qdot + B_ * Q_;                   // B*D   = 24,576

    k_dots<<<(B_ * C_ + B_ * Q_) / 4, 256, 0, stream>>>(cont, ques, SW, cdot, qdot);
    k_sim<<<dim3(C_ / 64, Q_ / 64, B_), 256, 0, stream>>>(cont, ques, SW, cdot, qdot, S);
    k_colstats<<<B_, 512, 0, stream>>>(S, colM, colInvL);
    k_rowmax<<<B_ * C_ / 4, 256, 0, stream>>>(S, Smax);
    k_cdash<<<dim3(B_, 3), 256, 0, stream>>>(cont, cmask, Smax, cdash);
    k_final<<<dim3(C_ / 64, D_ / 64, B_), 256, 0, stream>>>(cont, ques, qmask, S, colM, colInvL, cdash, out);
}

// Round 4
// 358.437 us; speedup vs baseline: 1.1438x; 1.1438x over previous
//
#include <hip/hip_runtime.h>
#include <hip/hip_bf16.h>

#define B_ 32
#define C_ 512
#define Q_ 128
#define D_ 768
constexpr float NEGV = -1e30f;
constexpr float CINV = 1.0f / 512.0f;

typedef short bf16x8 __attribute__((ext_vector_type(8)));
typedef short bf16x4 __attribute__((ext_vector_type(4)));
typedef float f32x4 __attribute__((ext_vector_type(4)));

__device__ __forceinline__ short f2bf(float x) {
    union { float f; unsigned u; } v; v.f = x;
    unsigned r = v.u + 0x7fffu + ((v.u >> 16) & 1u);
    return (short)(r >> 16);
}

// ---------------- K1: cdot[b,c] = cont . w1 ; qdot[b,q] = ques . w2 (wave per row)
__global__ void k_dots(const float* __restrict__ cont, const float* __restrict__ ques,
                       const float* __restrict__ SW, float* __restrict__ cdot,
                       float* __restrict__ qdot) {
    int w = threadIdx.x >> 6;
    int lane = threadIdx.x & 63;
    int r = blockIdx.x * 4 + w;
    const float* row;
    const float* wv;
    if (r < B_ * C_) { row = cont + (size_t)r * D_; wv = SW; }
    else             { row = ques + (size_t)(r - B_ * C_) * D_; wv = SW + D_; }
    float s = 0.f;
#pragma unroll
    for (int i = 0; i < D_ / 64; ++i) {
        int d = lane + i * 64;
        s += row[d] * wv[d];
    }
#pragma unroll
    for (int off = 32; off; off >>= 1) s += __shfl_xor(s, off, 64);
    if (lane == 0) {
        if (r < B_ * C_) cdot[r] = s;
        else qdot[r - B_ * C_] = s;
    }
}

// ---------------- K2: bf16 MFMA sim GEMM, tile 64c x 128q (full Q), K=768, BK=32.
// 8 waves (512 thr): wave (mw=w>>2, nw=w&3) owns 32x32 -> acc[2][2] 16x16 frags.
// Epilogue: S = acc + cdot + qdot -> global; fused rowmax over q -> Smax.
__global__ void __launch_bounds__(512) k_sim(const float* __restrict__ cont,
                                             const float* __restrict__ ques,
                                             const float* __restrict__ SW,
                                             const float* __restrict__ cdot,
                                             const float* __restrict__ qdot,
                                             float* __restrict__ S,
                                             float* __restrict__ Smax) {
    const int b = blockIdx.y, c0 = blockIdx.x * 64;
    __shared__ short Alds[64 * 32];    // [row c][k] bf16, row stride 64B, slot-swizzled
    __shared__ short Blds[128 * 32];   // [row q][k] bf16
    __shared__ float rowpart[4][64];
    char* Ab = (char*)Alds;
    char* Bb = (char*)Blds;
    const int t = threadIdx.x;
    const int w = t >> 6, l = t & 63;
    const int woffm = (w >> 2) * 32, woffn = (w & 3) * 32;
    const int lhi = l >> 4, llo = l & 15;
    f32x4 acc[2][2] = {};

    // staging indices
    const int arow = t >> 3, akq = (t & 7) * 4;       // A: 64 rows x 32k, 4 floats/thr
    const int brow = t >> 2, bkq = (t & 3) * 8;       // B: 128 rows x 32k, 8 floats/thr
    const float* Ap = cont + ((size_t)(b * C_ + c0 + arow)) * D_ + akq;
    const float* Bp = ques + ((size_t)(b * Q_ + brow)) * D_ + bkq;
    const float* w3 = SW + 2 * D_;
    const int aoff = arow * 64 + ((((akq >> 3) ^ (arow & 3)) << 4) | ((akq & 4) << 1));
    const int boff = brow * 64 + (((bkq >> 3) ^ (brow & 3)) << 4);

    for (int k0 = 0; k0 < D_; k0 += 32) {
        float4 av = *(const float4*)(Ap + k0);
        float4 w4 = *(const float4*)(w3 + k0 + akq);
        bf16x4 a4;
        a4[0] = f2bf(av.x * w4.x); a4[1] = f2bf(av.y * w4.y);
        a4[2] = f2bf(av.z * w4.z); a4[3] = f2bf(av.w * w4.w);
        *(bf16x4*)(Ab + aoff) = a4;
        float4 b0 = *(const float4*)(Bp + k0);
        float4 b1 = *(const float4*)(Bp + k0 + 4);
        bf16x8 b8;
        b8[0] = f2bf(b0.x); b8[1] = f2bf(b0.y); b8[2] = f2bf(b0.z); b8[3] = f2bf(b0.w);
        b8[4] = f2bf(b1.x); b8[5] = f2bf(b1.y); b8[6] = f2bf(b1.z); b8[7] = f2bf(b1.w);
        *(bf16x8*)(Bb + boff) = b8;
        __syncthreads();
        bf16x8 af[2], bfv[2];
#pragma unroll
        for (int mi = 0; mi < 2; ++mi) {
            int row = woffm + mi * 16 + llo;
            af[mi] = *(bf16x8*)(Ab + row * 64 + ((lhi ^ (row & 3)) << 4));
        }
#pragma unroll
        for (int ni = 0; ni < 2; ++ni) {
            int row = woffn + ni * 16 + llo;
            bfv[ni] = *(bf16x8*)(Bb + row * 64 + ((lhi ^ (row & 3)) << 4));
        }
#pragma unroll
        for (int mi = 0; mi < 2; ++mi)
#pragma unroll
            for (int ni = 0; ni < 2; ++ni)
                acc[mi][ni] = __builtin_amdgcn_mfma_f32_16x16x32_bf16(af[mi], bfv[ni], acc[mi][ni], 0, 0, 0);
        __syncthreads();
    }

    // epilogue: S + fused rowmax
    float qd0 = qdot[b * Q_ + woffn + llo];
    float qd1 = qdot[b * Q_ + woffn + 16 + llo];
#pragma unroll
    for (int mi = 0; mi < 2; ++mi) {
#pragma unroll
        for (int i = 0; i < 4; ++i) {
            int cl = woffm + mi * 16 + lhi * 4 + i;
            float cd = cdot[b * C_ + c0 + cl];
            size_t srow = ((size_t)(b * C_ + c0 + cl)) * Q_;
            float v0 = acc[mi][0][i] + cd + qd0;
            float v1 = acc[mi][1][i] + cd + qd1;
            S[srow + woffn + llo] = v0;
            S[srow + woffn + 16 + llo] = v1;
            float vm = fmaxf(v0, v1);
#pragma unroll
            for (int off = 1; off < 16; off <<= 1) vm = fmaxf(vm, __shfl_xor(vm, off, 64));
            if (llo == 0) rowpart[w & 3][cl] = vm;
        }
    }
    __syncthreads();
    if (t < 64) {
        float m = fmaxf(fmaxf(rowpart[0][t], rowpart[1][t]), fmaxf(rowpart[2][t], rowpart[3][t]));
        Smax[b * C_ + c0 + t] = m;
    }
}

// ---------------- K3: per (b,q): colM = max_c S, colInvL = 1/sum exp. 128 blocks.
__global__ void k_colstats(const float* __restrict__ S, float* __restrict__ colM,
                           float* __restrict__ colInvL) {
    int b = blockIdx.y;
    int ql = threadIdx.x & 31;
    int q = blockIdx.x * 32 + ql;
    int strip = threadIdx.x >> 5;   // 0..7, 64 c each
    float m = -INFINITY, l = 0.f;
    const float* Sp = S + ((size_t)(b * C_ + strip * 64)) * Q_ + q;
    for (int c = 0; c < 64; ++c) {
        float v = Sp[(size_t)c * Q_];
        if (v > m) { l = l * __expf(m - v) + 1.f; m = v; }
        else l += __expf(v - m);
    }
    __shared__ float sm[8][32], sl[8][32];
    sm[strip][ql] = m; sl[strip][ql] = l;
    __syncthreads();
    if (threadIdx.x < 32) {
        float M = sm[0][ql], L = sl[0][ql];
#pragma unroll
        for (int i = 1; i < 8; ++i) {
            float mi = sm[i][ql], li = sl[i][ql];
            if (mi > M) { L = L * __expf(M - mi) + li; M = mi; }
            else L += li * __expf(mi - M);
        }
        colM[b * Q_ + q] = M;
        colInvL[b * Q_ + q] = 1.f / L;
    }
}

// ---------------- K4: c_dash[b,d] = sum_c softmax_c(Smax + cmask)*cont. 384 blocks.
__global__ void k_cdash(const float* __restrict__ cont, const int* __restrict__ cmask,
                        const float* __restrict__ Smax, float* __restrict__ cdash) {
    int b = blockIdx.y, d0 = blockIdx.x * 64;
    __shared__ float dist[C_];
    __shared__ float red[256];
    __shared__ float ps[4][64];
    int t = threadIdx.x;
    float v0 = Smax[b * C_ + t]       + (cmask[b * C_ + t]       ? 0.f : NEGV);
    float v1 = Smax[b * C_ + t + 256] + (cmask[b * C_ + t + 256] ? 0.f : NEGV);
    float m = fmaxf(v0, v1);
    red[t] = m; __syncthreads();
    for (int s = 128; s; s >>= 1) { if (t < s) red[t] = fmaxf(red[t], red[t + s]); __syncthreads(); }
    m = red[0]; __syncthreads();
    float e0 = __expf(v0 - m), e1 = __expf(v1 - m);
    red[t] = e0 + e1; __syncthreads();
    for (int s = 128; s; s >>= 1) { if (t < s) red[t] += red[t + s]; __syncthreads(); }
    float inv = 1.f / red[0];
    dist[t] = e0 * inv; dist[t + 256] = e1 * inv;
    __syncthreads();
    int d = d0 + (t & 63), strip = t >> 6;
    float acc = 0.f;
    const float* cp = cont + ((size_t)(b * C_ + strip * 128)) * D_ + d;
#pragma unroll 4
    for (int c = 0; c < 128; ++c) acc += dist[strip * 128 + c] * cp[(size_t)c * D_];
    ps[strip][t & 63] = acc;
    __syncthreads();
    if (t < 64) cdash[b * D_ + d0 + t] = ps[0][t] + ps[1][t] + ps[2][t] + ps[3][t];
}

// ---------------- K5: c2q = dist @ ques via bf16 MFMA; fused 4-section epilogue.
// tile 64c x 64d, K=Q=128, BK=32. 4 waves (256 thr), wave (w>>1, w&1) owns 32x32.
__global__ void __launch_bounds__(256) k_final(const float* __restrict__ cont,
                                               const float* __restrict__ ques,
                                               const int* __restrict__ qmask,
                                               const float* __restrict__ S,
                                               const float* __restrict__ colM,
                                               const float* __restrict__ colInvL,
                                               const float* __restrict__ cdash,
                                               float* __restrict__ out) {
    const int b = blockIdx.z, c0 = blockIdx.x * 64, D0 = blockIdx.y * 64;
    __shared__ short Alds[64 * 32];    // dist [c][k=q] bf16
    __shared__ short BldsT[64 * 32];   // ques^T [d][k=q] bf16
    __shared__ float colMl[Q_];
    __shared__ float scl[Q_];          // qmask? colInvL : -1
    __shared__ float Cf[64][68];       // acc transpose for vectorized epilogue
    char* Ab = (char*)Alds;
    char* Bb = (char*)BldsT;
    const int t = threadIdx.x;
    const int w = t >> 6, l = t & 63;
    const int woffm = (w >> 1) * 32, woffn = (w & 1) * 32;
    const int lhi = l >> 4, llo = l & 15;
    f32x4 acc[2][2] = {};

    if (t < Q_) {
        colMl[t] = colM[b * Q_ + t];
        scl[t] = qmask[b * Q_ + t] ? colInvL[b * Q_ + t] : -1.f;
    }
    __syncthreads();

    const int arow = t >> 2, akq = (t & 3) * 8;   // A: 64 rows x 32 q, 8/thr
    const int qloc = t & 31, dgrp = t >> 5;       // B: 32 q x 64 d, 8/thr
    const int aoff = arow * 64 + (((akq >> 3) ^ (arow & 3)) << 4);

    for (int kk = 0; kk < 4; ++kk) {
        const int q0 = kk * 32;
        // A stage: dist from S
        {
            const float* sp = S + ((size_t)(b * C_ + c0 + arow)) * Q_ + q0 + akq;
            float4 s0 = *(const float4*)sp;
            float4 s1 = *(const float4*)(sp + 4);
            float sv[8] = {s0.x, s0.y, s0.z, s0.w, s1.x, s1.y, s1.z, s1.w};
            bf16x8 a8;
#pragma unroll
            for (int j = 0; j < 8; ++j) {
                int q = q0 + akq + j;
                float sc = scl[q];
                float dist = (sc < 0.f) ? CINV : __expf(sv[j] - colMl[q]) * sc;
                a8[j] = f2bf(dist);
            }
            *(bf16x8*)(Ab + aoff) = a8;
        }
        // B stage: ques transposed into [d][q]
        {
            const float* qp = ques + ((size_t)(b * Q_ + q0 + qloc)) * D_ + D0 + dgrp * 8;
            float4 b0 = *(const float4*)qp;
            float4 b1 = *(const float4*)(qp + 4);
            float bv[8] = {b0.x, b0.y, b0.z, b0.w, b1.x, b1.y, b1.z, b1.w};
#pragma unroll
            for (int j = 0; j < 8; ++j) {
                int d = dgrp * 8 + j;
                int byte = d * 64 + ((((qloc >> 3) ^ (d & 3)) << 4) | ((qloc & 7) * 2));
                *(short*)(Bb + byte) = f2bf(bv[j]);
            }
        }
        __syncthreads();
        bf16x8 af[2], bfv[2];
#pragma unroll
        for (int mi = 0; mi < 2; ++mi) {
            int row = woffm + mi * 16 + llo;
            af[mi] = *(bf16x8*)(Ab + row * 64 + ((lhi ^ (row & 3)) << 4));
        }
#pragma unroll
        for (int ni = 0; ni < 2; ++ni) {
            int row = woffn + ni * 16 + llo;
            bfv[ni] = *(bf16x8*)(Bb + row * 64 + ((lhi ^ (row & 3)) << 4));
        }
#pragma unroll
        for (int mi = 0; mi < 2; ++mi)
#pragma unroll
            for (int ni = 0; ni < 2; ++ni)
                acc[mi][ni] = __builtin_amdgcn_mfma_f32_16x16x32_bf16(af[mi], bfv[ni], acc[mi][ni], 0, 0, 0);
        __syncthreads();
    }

    // transpose acc through LDS, then vectorized 4-section epilogue
#pragma unroll
    for (int mi = 0; mi < 2; ++mi)
#pragma unroll
        for (int ni = 0; ni < 2; ++ni)
#pragma unroll
            for (int i = 0; i < 4; ++i)
                Cf[woffm + mi * 16 + lhi * 4 + i][woffn + ni * 16 + llo] = acc[mi][ni][i];
    __syncthreads();

    const int r = t >> 2, dch = (t & 3) * 16;
    const int cg = c0 + r;
    const float* cp = cont + ((size_t)(b * C_ + cg)) * D_ + D0 + dch;
    const float* dp = cdash + b * D_ + D0 + dch;
    float* op = out + ((size_t)(b * C_ + cg)) * (size_t)(4 * D_) + D0 + dch;
#pragma unroll
    for (int j = 0; j < 4; ++j) {
        float4 cv = *(const float4*)(cp + 4 * j);
        float4 av = *(const float4*)&Cf[r][dch + 4 * j];
        float4 dv = *(const float4*)(dp + 4 * j);
        float4 m1 = {cv.x * av.x, cv.y * av.y, cv.z * av.z, cv.w * av.w};
        float4 m2 = {cv.x * dv.x, cv.y * dv.y, cv.z * dv.z, cv.w * dv.w};
        *(float4*)(op + 4 * j) = cv;
        *(float4*)(op + D_ + 4 * j) = av;
        *(float4*)(op + 2 * D_ + 4 * j) = m1;
        *(float4*)(op + 3 * D_ + 4 * j) = m2;
    }
}

extern "C" void kernel_launch(void* const* d_in, const int* in_sizes, int n_in,
                              void* d_out, int out_size, void* d_ws, size_t ws_size,
                              hipStream_t stream) {
    const float* cont  = (const float*)d_in[0];
    const int*   cmask = (const int*)d_in[1];
    const float* ques  = (const float*)d_in[2];
    const int*   qmask = (const int*)d_in[3];
    const float* SW    = (const float*)d_in[4];
    float* out = (float*)d_out;

    float* ws      = (float*)d_ws;
    float* S       = ws;                               // B*C*Q
    float* Smax    = S + (size_t)B_ * C_ * Q_;         // B*C
    float* colM    = Smax + B_ * C_;                   // B*Q
    float* colInvL = colM + B_ * Q_;                   // B*Q
    float* cdot    = colInvL + B_ * Q_;                // B*C
    float* qdot    = cdot + B_ * C_;                   // B*Q
    float* cdash   = qdot + B_ * Q_;                   // B*D

    k_dots<<<(B_ * C_ + B_ * Q_) / 4, 256, 0, stream>>>(cont, ques, SW, cdot, qdot);
    k_sim<<<dim3(C_ / 64, B_), 512, 0, stream>>>(cont, ques, SW, cdot, qdot, S, Smax);
    k_colstats<<<dim3(Q_ / 32, B_), 256, 0, stream>>>(S, colM, colInvL);
    k_cdash<<<dim3(D_ / 64, B_), 256, 0, stream>>>(cont, cmask, Smax, cdash);
    k_final<<<dim3(C_ / 64, D_ / 64, B_), 256, 0, stream>>>(cont, ques, qmask, S, colM, colInvL, cdash, out);
}

// Round 5
// 322.239 us; speedup vs baseline: 1.2722x; 1.1123x over previous
//
#include <hip/hip_runtime.h>
#include <hip/hip_bf16.h>

#define B_ 32
#define C_ 512
#define Q_ 128
#define D_ 768
constexpr float NEGV = -1e30f;
constexpr float CINV = 1.0f / 512.0f;

typedef short bf16x8 __attribute__((ext_vector_type(8)));
typedef short bf16x4 __attribute__((ext_vector_type(4)));
typedef float f32x4 __attribute__((ext_vector_type(4)));

__device__ __forceinline__ short f2bf(float x) {
    union { float f; unsigned u; } v; v.f = x;
    unsigned r = v.u + 0x7fffu + ((v.u >> 16) & 1u);
    return (short)(r >> 16);
}

// ---- K0 prep: bf16 conversions + fused row dots (replaces k_dots).
// cont rows: contw3_bf[r][k] = bf16(cont*w3), cdot[r] = cont.w1
// ques rows: ques_bf[r][k] = bf16(ques),      qdot[r] = ques.w2
__global__ void k_prep(const float* __restrict__ cont, const float* __restrict__ ques,
                       const float* __restrict__ SW, short* __restrict__ contw3,
                       short* __restrict__ quesbf, float* __restrict__ cdot,
                       float* __restrict__ qdot) {
    int lane = threadIdx.x & 63;
    int r = blockIdx.x * 4 + (threadIdx.x >> 6);
    float acc = 0.f;
    if (r < B_ * C_) {
        const float* row = cont + (size_t)r * D_;
        short* orow = contw3 + (size_t)r * D_;
#pragma unroll
        for (int i = 0; i < 3; ++i) {
            int k = i * 256 + lane * 4;
            float4 f = *(const float4*)(row + k);
            float4 a = *(const float4*)(SW + k);            // w1
            float4 m = *(const float4*)(SW + 2 * D_ + k);   // w3
            acc += f.x * a.x + f.y * a.y + f.z * a.z + f.w * a.w;
            bf16x4 p;
            p[0] = f2bf(f.x * m.x); p[1] = f2bf(f.y * m.y);
            p[2] = f2bf(f.z * m.z); p[3] = f2bf(f.w * m.w);
            *(bf16x4*)(orow + k) = p;
        }
#pragma unroll
        for (int off = 32; off; off >>= 1) acc += __shfl_xor(acc, off, 64);
        if (lane == 0) cdot[r] = acc;
    } else {
        int r2 = r - B_ * C_;
        const float* row = ques + (size_t)r2 * D_;
        short* orow = quesbf + (size_t)r2 * D_;
#pragma unroll
        for (int i = 0; i < 3; ++i) {
            int k = i * 256 + lane * 4;
            float4 f = *(const float4*)(row + k);
            float4 a = *(const float4*)(SW + D_ + k);       // w2
            acc += f.x * a.x + f.y * a.y + f.z * a.z + f.w * a.w;
            bf16x4 p;
            p[0] = f2bf(f.x); p[1] = f2bf(f.y); p[2] = f2bf(f.z); p[3] = f2bf(f.w);
            *(bf16x4*)(orow + k) = p;
        }
#pragma unroll
        for (int off = 32; off; off >>= 1) acc += __shfl_xor(acc, off, 64);
        if (lane == 0) qdot[r2] = acc;
    }
}

// ---- K0b: transpose quesbf [q][d] -> quesT [d][q] per batch, 64x64 LDS tiles.
__global__ void k_qt(const short* __restrict__ quesbf, short* __restrict__ quesT) {
    const int d0 = blockIdx.x * 64, q0 = blockIdx.y * 64, b = blockIdx.z;
    __shared__ short T[64][65];
    const int t = threadIdx.x;
#pragma unroll
    for (int p = 0; p < 2; ++p) {
        int ql = p * 32 + (t >> 3), dl = (t & 7) * 8;
        bf16x8 v = *(const bf16x8*)(quesbf + ((size_t)(b * Q_ + q0 + ql)) * D_ + d0 + dl);
#pragma unroll
        for (int j = 0; j < 8; ++j) T[ql][dl + j] = v[j];
    }
    __syncthreads();
#pragma unroll
    for (int p = 0; p < 2; ++p) {
        int dl = p * 32 + (t >> 3), ql = (t & 7) * 8;
        bf16x8 v;
#pragma unroll
        for (int j = 0; j < 8; ++j) v[j] = T[ql + j][dl];
        *(bf16x8*)(quesT + ((size_t)(b * D_ + d0 + dl)) * Q_ + q0 + ql) = v;
    }
}

// ---- K1 sim GEMM: no LDS staging; frags direct from L2-resident bf16 arrays.
// tile 32c x 128q, 4 waves: wave w owns q-strip w*32. Fused rowmax -> Smax.
__global__ void __launch_bounds__(256) k_sim(const short* __restrict__ contw3,
                                             const short* __restrict__ quesbf,
                                             const float* __restrict__ cdot,
                                             const float* __restrict__ qdot,
                                             float* __restrict__ S,
                                             float* __restrict__ Smax) {
    const int b = blockIdx.y, c0 = blockIdx.x * 32;
    const int t = threadIdx.x, w = t >> 6, l = t & 63;
    const int llo = l & 15, lhi = l >> 4;
    __shared__ float rowpart[4][32];
    const short* Ab = contw3 + ((size_t)(b * C_ + c0)) * D_ + lhi * 8;
    const short* Bb = quesbf + ((size_t)(b * Q_ + w * 32)) * D_ + lhi * 8;
    f32x4 acc[2][2] = {};
#pragma unroll 4
    for (int k0 = 0; k0 < D_; k0 += 32) {
        bf16x8 a0 = *(const bf16x8*)(Ab + (size_t)llo * D_ + k0);
        bf16x8 a1 = *(const bf16x8*)(Ab + (size_t)(16 + llo) * D_ + k0);
        bf16x8 b0 = *(const bf16x8*)(Bb + (size_t)llo * D_ + k0);
        bf16x8 b1 = *(const bf16x8*)(Bb + (size_t)(16 + llo) * D_ + k0);
        acc[0][0] = __builtin_amdgcn_mfma_f32_16x16x32_bf16(a0, b0, acc[0][0], 0, 0, 0);
        acc[0][1] = __builtin_amdgcn_mfma_f32_16x16x32_bf16(a0, b1, acc[0][1], 0, 0, 0);
        acc[1][0] = __builtin_amdgcn_mfma_f32_16x16x32_bf16(a1, b0, acc[1][0], 0, 0, 0);
        acc[1][1] = __builtin_amdgcn_mfma_f32_16x16x32_bf16(a1, b1, acc[1][1], 0, 0, 0);
    }
    float qd0 = qdot[b * Q_ + w * 32 + llo];
    float qd1 = qdot[b * Q_ + w * 32 + 16 + llo];
#pragma unroll
    for (int mi = 0; mi < 2; ++mi) {
#pragma unroll
        for (int i = 0; i < 4; ++i) {
            int cl = mi * 16 + lhi * 4 + i;
            float cd = cdot[b * C_ + c0 + cl];
            size_t srow = ((size_t)(b * C_ + c0 + cl)) * Q_;
            float v0 = acc[mi][0][i] + cd + qd0;
            float v1 = acc[mi][1][i] + cd + qd1;
            S[srow + w * 32 + llo] = v0;
            S[srow + w * 32 + 16 + llo] = v1;
            float vm = fmaxf(v0, v1);
#pragma unroll
            for (int off = 1; off < 16; off <<= 1) vm = fmaxf(vm, __shfl_xor(vm, off, 64));
            if (llo == 0) rowpart[w][cl] = vm;
        }
    }
    __syncthreads();
    if (t < 32)
        Smax[b * C_ + c0 + t] = fmaxf(fmaxf(rowpart[0][t], rowpart[1][t]),
                                      fmaxf(rowpart[2][t], rowpart[3][t]));
}

// ---- K2: per (b,q): colM = max_c S; scl = qmask ? 1/sum exp : -1.
__global__ void k_colstats(const float* __restrict__ S, const int* __restrict__ qmask,
                           float* __restrict__ colM, float* __restrict__ scl) {
    const int b = blockIdx.y;
    const int ql = threadIdx.x & 15, q = blockIdx.x * 16 + ql;
    const int strip = threadIdx.x >> 4;   // 16 strips x 32 c
    float m = -INFINITY, lsum = 0.f;
    const float* Sp = S + ((size_t)(b * C_ + strip * 32)) * Q_ + q;
    for (int c = 0; c < 32; ++c) {
        float v = Sp[(size_t)c * Q_];
        if (v > m) { lsum = lsum * __expf(m - v) + 1.f; m = v; }
        else lsum += __expf(v - m);
    }
    __shared__ float sm[16][16], sl[16][16];
    sm[strip][ql] = m; sl[strip][ql] = lsum;
    __syncthreads();
    if (threadIdx.x < 16) {
        float M = sm[0][ql], L = sl[0][ql];
#pragma unroll
        for (int i = 1; i < 16; ++i) {
            float mi = sm[i][ql], li = sl[i][ql];
            if (mi > M) { L = L * __expf(M - mi) + li; M = mi; }
            else L += li * __expf(mi - M);
        }
        colM[b * Q_ + q] = M;
        scl[b * Q_ + q] = qmask[b * Q_ + q] ? 1.f / L : -1.f;
    }
}

// ---- K3: materialize bf16 dist once (kills 12x exp recompute in k_final).
__global__ void k_dist(const float* __restrict__ S, const float* __restrict__ colM,
                       const float* __restrict__ scl, short* __restrict__ distbf) {
    const int r = blockIdx.x * 16 + (threadIdx.x >> 4);      // global (b*C+c) row
    const int b = r >> 9;
    const int q8 = (threadIdx.x & 15) * 8;
    const float* sp = S + (size_t)r * Q_ + q8;
    float4 s0 = *(const float4*)sp;
    float4 s1 = *(const float4*)(sp + 4);
    float4 m0 = *(const float4*)(colM + b * Q_ + q8);
    float4 m1 = *(const float4*)(colM + b * Q_ + q8 + 4);
    float4 c0 = *(const float4*)(scl + b * Q_ + q8);
    float4 c1 = *(const float4*)(scl + b * Q_ + q8 + 4);
    float sv[8] = {s0.x, s0.y, s0.z, s0.w, s1.x, s1.y, s1.z, s1.w};
    float mv[8] = {m0.x, m0.y, m0.z, m0.w, m1.x, m1.y, m1.z, m1.w};
    float cv[8] = {c0.x, c0.y, c0.z, c0.w, c1.x, c1.y, c1.z, c1.w};
    bf16x8 o;
#pragma unroll
    for (int j = 0; j < 8; ++j)
        o[j] = f2bf(cv[j] < 0.f ? CINV : __expf(sv[j] - mv[j]) * cv[j]);
    *(bf16x8*)(distbf + (size_t)r * Q_ + q8) = o;
}

// ---- K4: c_dash[b,d] = sum_c softmax_c(Smax + cmask)*cont.
__global__ void k_cdash(const float* __restrict__ cont, const int* __restrict__ cmask,
                        const float* __restrict__ Smax, float* __restrict__ cdash) {
    int b = blockIdx.y, d0 = blockIdx.x * 64;
    __shared__ float dist[C_];
    __shared__ float red[256];
    __shared__ float ps[4][64];
    int t = threadIdx.x;
    float v0 = Smax[b * C_ + t]       + (cmask[b * C_ + t]       ? 0.f : NEGV);
    float v1 = Smax[b * C_ + t + 256] + (cmask[b * C_ + t + 256] ? 0.f : NEGV);
    float m = fmaxf(v0, v1);
    red[t] = m; __syncthreads();
    for (int s = 128; s; s >>= 1) { if (t < s) red[t] = fmaxf(red[t], red[t + s]); __syncthreads(); }
    m = red[0]; __syncthreads();
    float e0 = __expf(v0 - m), e1 = __expf(v1 - m);
    red[t] = e0 + e1; __syncthreads();
    for (int s = 128; s; s >>= 1) { if (t < s) red[t] += red[t + s]; __syncthreads(); }
    float inv = 1.f / red[0];
    dist[t] = e0 * inv; dist[t + 256] = e1 * inv;
    __syncthreads();
    int d = d0 + (t & 63), strip = t >> 6;
    float acc = 0.f;
    const float* cp = cont + ((size_t)(b * C_ + strip * 128)) * D_ + d;
#pragma unroll 8
    for (int c = 0; c < 128; ++c) acc += dist[strip * 128 + c] * cp[(size_t)c * D_];
    ps[strip][t & 63] = acc;
    __syncthreads();
    if (t < 64) cdash[b * D_ + d0 + t] = ps[0][t] + ps[1][t] + ps[2][t] + ps[3][t];
}

// ---- K5 final GEMM: c2q = dist @ ques, no LDS staging, fused 4-section epilogue.
// tile 64c x 64d, K=Q=128 unrolled. 4 waves, wave (w>>1, w&1) owns 32x32.
__global__ void __launch_bounds__(256) k_final(const float* __restrict__ cont,
                                               const short* __restrict__ distbf,
                                               const short* __restrict__ quesT,
                                               const float* __restrict__ cdash,
                                               float* __restrict__ out) {
    const int b = blockIdx.z, c0 = blockIdx.x * 64, D0 = blockIdx.y * 64;
    const int t = threadIdx.x, w = t >> 6, l = t & 63;
    const int woffm = (w >> 1) * 32, woffn = (w & 1) * 32;
    const int llo = l & 15, lhi = l >> 4;
    __shared__ float Cf[64][68];
    const short* Ab = distbf + ((size_t)(b * C_ + c0 + woffm)) * Q_ + lhi * 8;
    const short* Bb = quesT + ((size_t)(b * D_ + D0 + woffn)) * Q_ + lhi * 8;
    f32x4 acc[2][2] = {};
#pragma unroll
    for (int kk = 0; kk < 4; ++kk) {
        const int k0 = kk * 32;
        bf16x8 a0 = *(const bf16x8*)(Ab + llo * Q_ + k0);
        bf16x8 a1 = *(const bf16x8*)(Ab + (16 + llo) * Q_ + k0);
        bf16x8 b0 = *(const bf16x8*)(Bb + llo * Q_ + k0);
        bf16x8 b1 = *(const bf16x8*)(Bb + (16 + llo) * Q_ + k0);
        acc[0][0] = __builtin_amdgcn_mfma_f32_16x16x32_bf16(a0, b0, acc[0][0], 0, 0, 0);
        acc[0][1] = __builtin_amdgcn_mfma_f32_16x16x32_bf16(a0, b1, acc[0][1], 0, 0, 0);
        acc[1][0] = __builtin_amdgcn_mfma_f32_16x16x32_bf16(a1, b0, acc[1][0], 0, 0, 0);
        acc[1][1] = __builtin_amdgcn_mfma_f32_16x16x32_bf16(a1, b1, acc[1][1], 0, 0, 0);
    }
#pragma unroll
    for (int mi = 0; mi < 2; ++mi)
#pragma unroll
        for (int ni = 0; ni < 2; ++ni)
#pragma unroll
            for (int i = 0; i < 4; ++i)
                Cf[woffm + mi * 16 + lhi * 4 + i][woffn + ni * 16 + llo] = acc[mi][ni][i];
    __syncthreads();
    // coalesced epilogue: 16 lanes x 16B = 256B contiguous per row-section
    const int col = (t & 15) * 4;
    const float4 dv = *(const float4*)(cdash + b * D_ + D0 + col);
#pragma unroll
    for (int p = 0; p < 4; ++p) {
        int r = p * 16 + (t >> 4);
        float4 av = *(const float4*)&Cf[r][col];
        const float* cp = cont + ((size_t)(b * C_ + c0 + r)) * D_ + D0 + col;
        float4 cv = *(const float4*)cp;
        float4 m1 = {cv.x * av.x, cv.y * av.y, cv.z * av.z, cv.w * av.w};
        float4 m2 = {cv.x * dv.x, cv.y * dv.y, cv.z * dv.z, cv.w * dv.w};
        float* op = out + ((size_t)(b * C_ + c0 + r)) * (size_t)(4 * D_) + D0 + col;
        *(float4*)op = cv;
        *(float4*)(op + D_) = av;
        *(float4*)(op + 2 * D_) = m1;
        *(float4*)(op + 3 * D_) = m2;
    }
}

extern "C" void kernel_launch(void* const* d_in, const int* in_sizes, int n_in,
                              void* d_out, int out_size, void* d_ws, size_t ws_size,
                              hipStream_t stream) {
    const float* cont  = (const float*)d_in[0];
    const int*   cmask = (const int*)d_in[1];
    const float* ques  = (const float*)d_in[2];
    const int*   qmask = (const int*)d_in[3];
    const float* SW    = (const float*)d_in[4];
    float* out = (float*)d_out;

    float* ws      = (float*)d_ws;
    float* S       = ws;                               // B*C*Q f32
    float* Smax    = S + (size_t)B_ * C_ * Q_;         // B*C
    float* colM    = Smax + B_ * C_;                   // B*Q
    float* scl     = colM + B_ * Q_;                   // B*Q
    float* cdot    = scl + B_ * Q_;                    // B*C
    float* qdot    = cdot + B_ * C_;                   // B*Q
    float* cdash   = qdot + B_ * Q_;                   // B*D
    short* contw3  = (short*)(cdash + B_ * D_);        // B*C*D bf16
    short* quesbf  = contw3 + (size_t)B_ * C_ * D_;    // B*Q*D
    short* quesT   = quesbf + (size_t)B_ * Q_ * D_;    // B*D*Q
    short* distbf  = quesT + (size_t)B_ * D_ * Q_;     // B*C*Q

    k_prep<<<(B_ * C_ + B_ * Q_) / 4, 256, 0, stream>>>(cont, ques, SW, contw3, quesbf, cdot, qdot);
    k_qt<<<dim3(D_ / 64, Q_ / 64, B_), 256, 0, stream>>>(quesbf, quesT);
    k_sim<<<dim3(C_ / 32, B_), 256, 0, stream>>>(contw3, quesbf, cdot, qdot, S, Smax);
    k_colstats<<<dim3(Q_ / 16, B_), 256, 0, stream>>>(S, qmask, colM, scl);
    k_dist<<<B_ * C_ / 16, 256, 0, stream>>>(S, colM, scl, distbf);
    k_cdash<<<dim3(D_ / 64, B_), 256, 0, stream>>>(cont, cmask, Smax, cdash);
    k_final<<<dim3(C_ / 64, D_ / 64, B_), 256, 0, stream>>>(cont, distbf, quesT, cdash, out);
}

// Round 7
// 321.553 us; speedup vs baseline: 1.2750x; 1.0021x over previous
//
#include <hip/hip_runtime.h>
#include <hip/hip_bf16.h>

#define B_ 32
#define C_ 512
#define Q_ 128
#define D_ 768
constexpr float NEGV = -1e30f;
constexpr float CINV = 1.0f / 512.0f;

typedef short bf16x8 __attribute__((ext_vector_type(8)));
typedef short bf16x4 __attribute__((ext_vector_type(4)));
typedef float f32x4 __attribute__((ext_vector_type(4)));

__device__ __forceinline__ short f2bf(float x) {
    union { float f; unsigned u; } v; v.f = x;
    unsigned r = v.u + 0x7fffu + ((v.u >> 16) & 1u);
    return (short)(r >> 16);
}

__device__ __forceinline__ void nt_store4(float* p, float x, float y, float z, float w) {
    f32x4 v = {x, y, z, w};
    __builtin_nontemporal_store(v, (f32x4*)p);
}

// ---- K0 prep: bf16 conversions + fused row dots.
__global__ void k_prep(const float* __restrict__ cont, const float* __restrict__ ques,
                       const float* __restrict__ SW, short* __restrict__ contw3,
                       short* __restrict__ quesbf, float* __restrict__ cdot,
                       float* __restrict__ qdot) {
    int lane = threadIdx.x & 63;
    int r = blockIdx.x * 4 + (threadIdx.x >> 6);
    float acc = 0.f;
    if (r < B_ * C_) {
        const float* row = cont + (size_t)r * D_;
        short* orow = contw3 + (size_t)r * D_;
#pragma unroll
        for (int i = 0; i < 3; ++i) {
            int k = i * 256 + lane * 4;
            float4 f = *(const float4*)(row + k);
            float4 a = *(const float4*)(SW + k);            // w1
            float4 m = *(const float4*)(SW + 2 * D_ + k);   // w3
            acc += f.x * a.x + f.y * a.y + f.z * a.z + f.w * a.w;
            bf16x4 p;
            p[0] = f2bf(f.x * m.x); p[1] = f2bf(f.y * m.y);
            p[2] = f2bf(f.z * m.z); p[3] = f2bf(f.w * m.w);
            *(bf16x4*)(orow + k) = p;
        }
#pragma unroll
        for (int off = 32; off; off >>= 1) acc += __shfl_xor(acc, off, 64);
        if (lane == 0) cdot[r] = acc;
    } else {
        int r2 = r - B_ * C_;
        const float* row = ques + (size_t)r2 * D_;
        short* orow = quesbf + (size_t)r2 * D_;
#pragma unroll
        for (int i = 0; i < 3; ++i) {
            int k = i * 256 + lane * 4;
            float4 f = *(const float4*)(row + k);
            float4 a = *(const float4*)(SW + D_ + k);       // w2
            acc += f.x * a.x + f.y * a.y + f.z * a.z + f.w * a.w;
            bf16x4 p;
            p[0] = f2bf(f.x); p[1] = f2bf(f.y); p[2] = f2bf(f.z); p[3] = f2bf(f.w);
            *(bf16x4*)(orow + k) = p;
        }
#pragma unroll
        for (int off = 32; off; off >>= 1) acc += __shfl_xor(acc, off, 64);
        if (lane == 0) qdot[r2] = acc;
    }
}

// ---- K1 sim GEMM: direct-from-L2 MFMA, tile 32c x 128q; fused rowmax -> Smax.
__global__ void __launch_bounds__(256) k_sim(const short* __restrict__ contw3,
                                             const short* __restrict__ quesbf,
                                             const float* __restrict__ cdot,
                                             const float* __restrict__ qdot,
                                             float* __restrict__ S,
                                             float* __restrict__ Smax) {
    const int b = blockIdx.y, c0 = blockIdx.x * 32;
    const int t = threadIdx.x, w = t >> 6, l = t & 63;
    const int llo = l & 15, lhi = l >> 4;
    __shared__ float rowpart[4][32];
    const short* Ab = contw3 + ((size_t)(b * C_ + c0)) * D_ + lhi * 8;
    const short* Bb = quesbf + ((size_t)(b * Q_ + w * 32)) * D_ + lhi * 8;
    f32x4 acc[2][2] = {};
#pragma unroll 4
    for (int k0 = 0; k0 < D_; k0 += 32) {
        bf16x8 a0 = *(const bf16x8*)(Ab + (size_t)llo * D_ + k0);
        bf16x8 a1 = *(const bf16x8*)(Ab + (size_t)(16 + llo) * D_ + k0);
        bf16x8 b0 = *(const bf16x8*)(Bb + (size_t)llo * D_ + k0);
        bf16x8 b1 = *(const bf16x8*)(Bb + (size_t)(16 + llo) * D_ + k0);
        acc[0][0] = __builtin_amdgcn_mfma_f32_16x16x32_bf16(a0, b0, acc[0][0], 0, 0, 0);
        acc[0][1] = __builtin_amdgcn_mfma_f32_16x16x32_bf16(a0, b1, acc[0][1], 0, 0, 0);
        acc[1][0] = __builtin_amdgcn_mfma_f32_16x16x32_bf16(a1, b0, acc[1][0], 0, 0, 0);
        acc[1][1] = __builtin_amdgcn_mfma_f32_16x16x32_bf16(a1, b1, acc[1][1], 0, 0, 0);
    }
    float qd0 = qdot[b * Q_ + w * 32 + llo];
    float qd1 = qdot[b * Q_ + w * 32 + 16 + llo];
#pragma unroll
    for (int mi = 0; mi < 2; ++mi) {
#pragma unroll
        for (int i = 0; i < 4; ++i) {
            int cl = mi * 16 + lhi * 4 + i;
            float cd = cdot[b * C_ + c0 + cl];
            size_t srow = ((size_t)(b * C_ + c0 + cl)) * Q_;
            float v0 = acc[mi][0][i] + cd + qd0;
            float v1 = acc[mi][1][i] + cd + qd1;
            S[srow + w * 32 + llo] = v0;
            S[srow + w * 32 + 16 + llo] = v1;
            float vm = fmaxf(v0, v1);
#pragma unroll
            for (int off = 1; off < 16; off <<= 1) vm = fmaxf(vm, __shfl_xor(vm, off, 64));
            if (llo == 0) rowpart[w][cl] = vm;
        }
    }
    __syncthreads();
    if (t < 32)
        Smax[b * C_ + c0 + t] = fmaxf(fmaxf(rowpart[0][t], rowpart[1][t]),
                                      fmaxf(rowpart[2][t], rowpart[3][t]));
}

// ---- K2 fused middle kernel, three block types on grid.x:
//   [0,8):   colstats + dist materialization for a 16-q strip
//   [8,20):  c_dash for a 64-d strip
//   [20,44): ques transpose 64x64 tile
__global__ void __launch_bounds__(256) k_mid(const float* __restrict__ S,
                                             const int* __restrict__ qmask,
                                             const float* __restrict__ cont,
                                             const int* __restrict__ cmask,
                                             const float* __restrict__ Smax,
                                             const short* __restrict__ quesbf,
                                             short* __restrict__ distbf,
                                             float* __restrict__ cdash,
                                             short* __restrict__ quesT) {
    const int b = blockIdx.y;
    const int t = threadIdx.x;
    if (blockIdx.x < 8) {
        // ---- colstats + dist ----
        const int q0 = blockIdx.x * 16;
        const int ql = t & 15, strip = t >> 4;   // 16 strips x 32 c
        __shared__ float sm[16][16], sl[16][16];
        __shared__ float colMl[16], scll[16];
        float m = -INFINITY, lsum = 0.f;
        const float* Sp = S + ((size_t)(b * C_ + strip * 32)) * Q_ + q0 + ql;
        for (int c = 0; c < 32; ++c) {
            float v = Sp[(size_t)c * Q_];
            if (v > m) { lsum = lsum * __expf(m - v) + 1.f; m = v; }
            else lsum += __expf(v - m);
        }
        sm[strip][ql] = m; sl[strip][ql] = lsum;
        __syncthreads();
        if (t < 16) {
            float M = sm[0][t], L = sl[0][t];
#pragma unroll
            for (int i = 1; i < 16; ++i) {
                float mi = sm[i][t], li = sl[i][t];
                if (mi > M) { L = L * __expf(M - mi) + li; M = mi; }
                else L += li * __expf(mi - M);
            }
            colMl[t] = M;
            scll[t] = qmask[b * Q_ + q0 + t] ? 1.f / L : -1.f;
        }
        __syncthreads();
        const float cm = colMl[ql], sc = scll[ql];
        short* dp = distbf + ((size_t)(b * C_ + strip * 32)) * Q_ + q0 + ql;
#pragma unroll 4
        for (int c = 0; c < 32; ++c) {
            float v = Sp[(size_t)c * Q_];
            float dist = (sc < 0.f) ? CINV : __expf(v - cm) * sc;
            dp[(size_t)c * Q_] = f2bf(dist);
        }
    } else if (blockIdx.x < 20) {
        // ---- c_dash ----
        const int d0 = (blockIdx.x - 8) * 64;
        __shared__ float dist[C_];
        __shared__ float red[256];
        __shared__ float ps[4][64];
        float v0 = Smax[b * C_ + t]       + (cmask[b * C_ + t]       ? 0.f : NEGV);
        float v1 = Smax[b * C_ + t + 256] + (cmask[b * C_ + t + 256] ? 0.f : NEGV);
        float m = fmaxf(v0, v1);
        red[t] = m; __syncthreads();
        for (int s = 128; s; s >>= 1) { if (t < s) red[t] = fmaxf(red[t], red[t + s]); __syncthreads(); }
        m = red[0]; __syncthreads();
        float e0 = __expf(v0 - m), e1 = __expf(v1 - m);
        red[t] = e0 + e1; __syncthreads();
        for (int s = 128; s; s >>= 1) { if (t < s) red[t] += red[t + s]; __syncthreads(); }
        float inv = 1.f / red[0];
        dist[t] = e0 * inv; dist[t + 256] = e1 * inv;
        __syncthreads();
        int d = d0 + (t & 63), strip = t >> 6;
        float acc = 0.f;
        const float* cp = cont + ((size_t)(b * C_ + strip * 128)) * D_ + d;
#pragma unroll 8
        for (int c = 0; c < 128; ++c) acc += dist[strip * 128 + c] * cp[(size_t)c * D_];
        ps[strip][t & 63] = acc;
        __syncthreads();
        if (t < 64) cdash[b * D_ + d0 + t] = ps[0][t] + ps[1][t] + ps[2][t] + ps[3][t];
    } else {
        // ---- ques transpose: quesbf [q][d] -> quesT [d][q], 64x64 tile ----
        const int tx = blockIdx.x - 20;            // 0..23
        const int d0 = (tx % 12) * 64, q0 = (tx / 12) * 64;
        __shared__ short T[64][65];
#pragma unroll
        for (int p = 0; p < 2; ++p) {
            int ql = p * 32 + (t >> 3), dl = (t & 7) * 8;
            bf16x8 v = *(const bf16x8*)(quesbf + ((size_t)(b * Q_ + q0 + ql)) * D_ + d0 + dl);
#pragma unroll
            for (int j = 0; j < 8; ++j) T[ql][dl + j] = v[j];
        }
        __syncthreads();
#pragma unroll
        for (int p = 0; p < 2; ++p) {
            int dl = p * 32 + (t >> 3), ql = (t & 7) * 8;
            bf16x8 v;
#pragma unroll
            for (int j = 0; j < 8; ++j) v[j] = T[ql + j][dl];
            *(bf16x8*)(quesT + ((size_t)(b * D_ + d0 + dl)) * Q_ + q0 + ql) = v;
        }
    }
}

// ---- K3 final GEMM: c2q = dist @ ques^T, fused 4-section epilogue, nt stores.
__global__ void __launch_bounds__(256) k_final(const float* __restrict__ cont,
                                               const short* __restrict__ distbf,
                                               const short* __restrict__ quesT,
                                               const float* __restrict__ cdash,
                                               float* __restrict__ out) {
    const int b = blockIdx.z, c0 = blockIdx.x * 64, D0 = blockIdx.y * 64;
    const int t = threadIdx.x, w = t >> 6, l = t & 63;
    const int woffm = (w >> 1) * 32, woffn = (w & 1) * 32;
    const int llo = l & 15, lhi = l >> 4;
    __shared__ float Cf[64][68];
    const short* Ab = distbf + ((size_t)(b * C_ + c0 + woffm)) * Q_ + lhi * 8;
    const short* Bb = quesT + ((size_t)(b * D_ + D0 + woffn)) * Q_ + lhi * 8;
    f32x4 acc[2][2] = {};
#pragma unroll
    for (int kk = 0; kk < 4; ++kk) {
        const int k0 = kk * 32;
        bf16x8 a0 = *(const bf16x8*)(Ab + llo * Q_ + k0);
        bf16x8 a1 = *(const bf16x8*)(Ab + (16 + llo) * Q_ + k0);
        bf16x8 b0 = *(const bf16x8*)(Bb + llo * Q_ + k0);
        bf16x8 b1 = *(const bf16x8*)(Bb + (16 + llo) * Q_ + k0);
        acc[0][0] = __builtin_amdgcn_mfma_f32_16x16x32_bf16(a0, b0, acc[0][0], 0, 0, 0);
        acc[0][1] = __builtin_amdgcn_mfma_f32_16x16x32_bf16(a0, b1, acc[0][1], 0, 0, 0);
        acc[1][0] = __builtin_amdgcn_mfma_f32_16x16x32_bf16(a1, b0, acc[1][0], 0, 0, 0);
        acc[1][1] = __builtin_amdgcn_mfma_f32_16x16x32_bf16(a1, b1, acc[1][1], 0, 0, 0);
    }
#pragma unroll
    for (int mi = 0; mi < 2; ++mi)
#pragma unroll
        for (int ni = 0; ni < 2; ++ni)
#pragma unroll
            for (int i = 0; i < 4; ++i)
                Cf[woffm + mi * 16 + lhi * 4 + i][woffn + ni * 16 + llo] = acc[mi][ni][i];
    __syncthreads();
    const int col = (t & 15) * 4;
    const float4 dv = *(const float4*)(cdash + b * D_ + D0 + col);
#pragma unroll
    for (int p = 0; p < 4; ++p) {
        int r = p * 16 + (t >> 4);
        float4 av = *(const float4*)&Cf[r][col];
        const float* cp = cont + ((size_t)(b * C_ + c0 + r)) * D_ + D0 + col;
        float4 cv = *(const float4*)cp;
        float* op = out + ((size_t)(b * C_ + c0 + r)) * (size_t)(4 * D_) + D0 + col;
        nt_store4(op, cv.x, cv.y, cv.z, cv.w);
        nt_store4(op + D_, av.x, av.y, av.z, av.w);
        nt_store4(op + 2 * D_, cv.x * av.x, cv.y * av.y, cv.z * av.z, cv.w * av.w);
        nt_store4(op + 3 * D_, cv.x * dv.x, cv.y * dv.y, cv.z * dv.z, cv.w * dv.w);
    }
}

extern "C" void kernel_launch(void* const* d_in, const int* in_sizes, int n_in,
                              void* d_out, int out_size, void* d_ws, size_t ws_size,
                              hipStream_t stream) {
    const float* cont  = (const float*)d_in[0];
    const int*   cmask = (const int*)d_in[1];
    const float* ques  = (const float*)d_in[2];
    const int*   qmask = (const int*)d_in[3];
    const float* SW    = (const float*)d_in[4];
    float* out = (float*)d_out;

    float* ws      = (float*)d_ws;
    float* S       = ws;                               // B*C*Q f32
    float* Smax    = S + (size_t)B_ * C_ * Q_;         // B*C
    float* cdot    = Smax + B_ * C_;                   // B*C
    float* qdot    = cdot + B_ * C_;                   // B*Q
    float* cdash   = qdot + B_ * Q_;                   // B*D
    short* contw3  = (short*)(cdash + B_ * D_);        // B*C*D bf16
    short* quesbf  = contw3 + (size_t)B_ * C_ * D_;    // B*Q*D
    short* quesT   = quesbf + (size_t)B_ * Q_ * D_;    // B*D*Q
    short* distbf  = quesT + (size_t)B_ * D_ * Q_;     // B*C*Q

    k_prep<<<(B_ * C_ + B_ * Q_) / 4, 256, 0, stream>>>(cont, ques, SW, contw3, quesbf, cdot, qdot);
    k_sim<<<dim3(C_ / 32, B_), 256, 0, stream>>>(contw3, quesbf, cdot, qdot, S, Smax);
    k_mid<<<dim3(44, B_), 256, 0, stream>>>(S, qmask, cont, cmask, Smax, quesbf, distbf, cdash, quesT);
    k_final<<<dim3(C_ / 64, D_ / 64, B_), 256, 0, stream>>>(cont, distbf, quesT, cdash, out);
}